// Round 3
// baseline (388.715 us; speedup 1.0000x reference)
//
#include <hip/hip_runtime.h>

// ProposalLayer for Faster R-CNN RPN on MI355X.
// B=4, H=64, W=96, A=9 anchors, N=55296 anchors/image.
// TEST cfg: pre=6000, post=300, thresh=0.7, min_size=16.

#define NB 4
#define AH 64
#define AW 96
#define NA 9
#define NPC (AH*AW*NA)      // 55296
#define CAP 16384           // candidate buffer per image
#define PREMAX 12000        // max 'pre' (TRAIN)
#define POSTMAX 2048        // max 'post' (TRAIN)
#define NBUCK 4096

// anchors from _generate_anchors(16, (0.5,1,2), (8,16,32)) — verified vs numpy
__constant__ float c_anchors[NA][4] = {
  { -84.f,  -40.f,  99.f,  55.f},
  {-176.f,  -88.f, 191.f, 103.f},
  {-360.f, -184.f, 375.f, 199.f},
  { -56.f,  -56.f,  71.f,  71.f},
  {-120.f, -120.f, 135.f, 135.f},
  {-248.f, -248.f, 263.f, 263.f},
  { -36.f,  -80.f,  51.f,  95.f},
  { -80.f, -168.f,  95.f, 183.f},
  {-168.f, -344.f, 183.f, 359.f},
};

// static scratch; invariant: g_hist all-zero and (g_cnt re-zeroed by k_pivot
// each call) — k_pivot both consumes and re-zeroes g_hist, so every call
// leaves the state a fresh call needs. First call sees .bss zeros.
__device__ unsigned int          g_keys[NB][NPC];
__device__ float4                g_boxes[NB][NPC];
__device__ unsigned int          g_hist[NB][NBUCK];
__device__ unsigned int          g_pivot[NB];
__device__ int                   g_cnt[NB];
__device__ unsigned long long    g_cand[NB][CAP];
__device__ float4                g_sbox[NB][PREMAX];

// exact-equivalent "iou > 0.7f" without a division on the hot path:
// |inter - 0.7*denom| > 4e-6*denom decides the sign safely (accumulated
// rounding < 1e-7 rel); the ~never-taken borderline falls back to the exact
// IEEE division the reference performs.
__device__ __forceinline__ bool iou_gt(float4 a, float areaA, float4 q, float areaQ) {
#pragma clang fp contract(off)
  float iw = fminf(a.z, q.z) - fmaxf(a.x, q.x) + 1.0f; iw = fmaxf(iw, 0.0f);
  float ih = fminf(a.w, q.w) - fmaxf(a.y, q.y) + 1.0f; ih = fmaxf(ih, 0.0f);
  float inter = iw * ih;
  float denom = areaA + areaQ - inter;
  float d = inter - 0.7f * denom;
  if (__builtin_expect(fabsf(d) <= 4e-6f * denom, 0))
    return (inter / denom) > 0.7f;
  return d > 0.0f;
}

__global__ void k_decode(const float* __restrict__ cls,
                         const float* __restrict__ dlt,
                         const float* __restrict__ ish) {
#pragma clang fp contract(off)
  int b = blockIdx.y;
  int i = blockIdx.x * blockDim.x + threadIdx.x;
  __shared__ unsigned int lh[NBUCK];
  for (int t = threadIdx.x; t < NBUCK; t += blockDim.x) lh[t] = 0u;
  __syncthreads();

  if (i < NPC) {
    int a   = i % NA;
    int pos = i / NA;
    int wx  = pos % AW;
    int hy  = pos / AW;

    float score = cls[((b * (2*NA) + NA + a) * AH + hy) * AW + wx];
    int dbase = ((b * (4*NA) + a*4) * AH + hy) * AW + wx;
    const int hw = AH * AW;
    float d0 = dlt[dbase];
    float d1 = dlt[dbase + hw];
    float d2 = dlt[dbase + 2*hw];
    float d3 = dlt[dbase + 3*hw];

    float shx = (float)(wx * 16);
    float shy = (float)(hy * 16);
    float ax1 = c_anchors[a][0] + shx;
    float ay1 = c_anchors[a][1] + shy;
    float ax2 = c_anchors[a][2] + shx;
    float ay2 = c_anchors[a][3] + shy;

    float aw_ = ax2 - ax1 + 1.0f;
    float ah_ = ay2 - ay1 + 1.0f;
    float acx = ax1 + 0.5f * aw_;
    float acy = ay1 + 0.5f * ah_;

    float pcx = d0 * aw_ + acx;
    float pcy = d1 * ah_ + acy;
    float pw  = expf(d2) * aw_;
    float ph  = expf(d3) * ah_;

    float x1 = pcx - 0.5f * pw;
    float y1 = pcy - 0.5f * ph;
    float x2 = pcx + 0.5f * pw;
    float y2 = pcy + 0.5f * ph;

    float imh = ish[b*2 + 0];
    float imw = ish[b*2 + 1];
    x1 = fminf(fmaxf(x1, 0.0f), imw - 1.0f);
    x2 = fminf(fmaxf(x2, 0.0f), imw - 1.0f);
    y1 = fminf(fmaxf(y1, 0.0f), imh - 1.0f);
    y2 = fminf(fmaxf(y2, 0.0f), imh - 1.0f);

    bool valid = ((x2 - x1 + 1.0f) >= 16.0f) && ((y2 - y1 + 1.0f) >= 16.0f);

    g_boxes[b][i] = make_float4(x1, y1, x2, y2);

    unsigned int key = 0u;
    if (valid) {
      unsigned int ub = __float_as_uint(score);
      key = (ub >> 31) ? ~ub : (ub | 0x80000000u);  // monotonic flip
    }
    g_keys[b][i] = key;
    atomicAdd(&lh[key >> 20], 1u);
  }
  __syncthreads();
  for (int t = threadIdx.x; t < NBUCK; t += blockDim.x)
    if (lh[t]) atomicAdd(&g_hist[b][t], lh[t]);
}

// per-image two-level pivot (coarse bucket, then 12 more bits) so the
// candidate count lands at pre + epsilon. Also re-zeroes g_hist and g_cnt.
__global__ void k_pivot(const int* __restrict__ train) {
  int b = blockIdx.x;
  int tid = threadIdx.x;  // 256
  unsigned int pre = train[0] ? 12000u : 6000u;
  __shared__ unsigned int h[NBUCK];
  __shared__ unsigned int csum[256];
  __shared__ unsigned int csuf[257];
  __shared__ int sBest;
  __shared__ unsigned int sHi;

  for (int t = tid; t < NBUCK; t += 256) { h[t] = g_hist[b][t]; g_hist[b][t] = 0u; }
  if (tid == 0) { sBest = 0; sHi = 0u; g_cnt[b] = 0; }
  __syncthreads();

  // ---- phase 1: coarse pivot P = largest q>=1 with suffix(q) >= pre
  unsigned int s = 0;
  for (int q = 0; q < 16; ++q) s += h[tid*16 + q];
  csum[tid] = s;
  __syncthreads();
  if (tid == 0) {
    unsigned int run = 0;
    csuf[256] = 0;
    for (int c = 255; c >= 0; --c) { run += csum[c]; csuf[c] = run; }
  }
  __syncthreads();
  {
    unsigned int run = csuf[tid + 1];
    int loc = 0;
    for (int q = tid*16 + 15; q >= tid*16; --q) {
      run += h[q];
      if (run >= pre && q >= 1) { loc = q; break; }
    }
    if (loc) atomicMax(&sBest, loc);
  }
  __syncthreads();
  int P = sBest;
  if (P == 0) {                       // fewer than pre valid candidates total
    if (tid == 0) g_pivot[b] = 1u;    // accept every valid (nonzero) key
    return;
  }

  // ---- sHi = count strictly above bucket P
  {
    unsigned int part = 0;
    for (int q = tid; q < NBUCK; q += 256) if (q > P) part += h[q];
    atomicAdd(&sHi, part);
  }
  __syncthreads();
  unsigned int pre2 = pre - sHi;      // >= 1 by construction of P
  __syncthreads();

  // ---- phase 2: sub-histogram of bits 19..8 within bucket P (reuse h)
  for (int t = tid; t < NBUCK; t += 256) h[t] = 0u;
  if (tid == 0) sBest = -1;
  __syncthreads();
  for (int i = tid; i < NPC; i += 256) {
    unsigned int key = g_keys[b][i];
    if ((key >> 20) == (unsigned int)P) atomicAdd(&h[(key >> 8) & 0xFFFu], 1u);
  }
  __syncthreads();

  s = 0;
  for (int q = 0; q < 16; ++q) s += h[tid*16 + q];
  csum[tid] = s;
  __syncthreads();
  if (tid == 0) {
    unsigned int run = 0;
    csuf[256] = 0;
    for (int c = 255; c >= 0; --c) { run += csum[c]; csuf[c] = run; }
  }
  __syncthreads();
  {
    unsigned int run = csuf[tid + 1];
    int loc = -1;
    for (int q = tid*16 + 15; q >= tid*16; --q) {
      run += h[q];
      if (run >= pre2) { loc = q; break; }
    }
    if (loc >= 0) atomicMax(&sBest, loc);
  }
  __syncthreads();
  if (tid == 0) {
    int Q = sBest; if (Q < 0) Q = 0;
    g_pivot[b] = (((unsigned int)P) << 20) | (((unsigned int)Q) << 8);
  }
}

__global__ void k_compact() {
  int b = blockIdx.y;
  int i = blockIdx.x * blockDim.x + threadIdx.x;
  if (i >= NPC) return;
  unsigned int key = g_keys[b][i];
  if (key != 0u && key >= g_pivot[b]) {
    int pos = atomicAdd(&g_cnt[b], 1);
    if (pos < CAP)
      g_cand[b][pos] = ((unsigned long long)key << 32) |
                       (unsigned long long)(0xFFFFFFFFu - (unsigned int)i);
  }
}

// exact rank (descending key, ascending index). The compare index k is
// block-uniform -> compiler scalarizes g_cand[b][k] to s_load bursts;
// per-element cost is ~2 VALU (v_cmp_gt_u64 + addc).
__global__ void k_rank(const int* __restrict__ train) {
  int b = blockIdx.y;
  int pre = train[0] ? 12000 : 6000;
  int Cb = g_cnt[b]; if (Cb > CAP) Cb = CAP;
  if ((int)(blockIdx.x * blockDim.x) >= Cb) return;   // uniform early-out
  int j = blockIdx.x * blockDim.x + threadIdx.x;

  unsigned long long cj = (j < Cb) ? g_cand[b][j] : ~0ull;
  const unsigned long long* __restrict__ cb = &g_cand[b][0];
  int rank = 0;
  int kmax = Cb & ~7;
  int k = 0;
  for (; k < kmax; k += 8) {
    rank += (int)(cb[k]   > cj) + (int)(cb[k+1] > cj)
          + (int)(cb[k+2] > cj) + (int)(cb[k+3] > cj)
          + (int)(cb[k+4] > cj) + (int)(cb[k+5] > cj)
          + (int)(cb[k+6] > cj) + (int)(cb[k+7] > cj);
  }
  for (; k < Cb; ++k) rank += (int)(cb[k] > cj);
  if (j < Cb && rank < pre) {
    unsigned int idx = 0xFFFFFFFFu - (unsigned int)(cj & 0xFFFFFFFFull);
    g_sbox[b][rank] = g_boxes[b][idx];
  }
}

// 4 waves per image: batched greedy NMS, 64 candidates per chunk.
// Exact-equivalent to the serial scan. Wave-split + unrolled suppression
// checks (8 LDS reads in flight), parallel 64x64 conflict-mask build,
// single-wave ballot resolve.
__global__ void __launch_bounds__(256)
k_nms(float* __restrict__ out, const int* __restrict__ train, int post) {
#pragma clang fp contract(off)
  int b = blockIdx.x;
  int tid = threadIdx.x;
  int lane = tid & 63;
  int wid = tid >> 6;
  int pre = train[0] ? 12000 : 6000;
  int Cb = g_cnt[b]; if (Cb > CAP) Cb = CAP;
  int Kb = min(pre, Cb);

  __shared__ float4 kbox[POSTMAX];
  __shared__ float  kar [POSTMAX];
  __shared__ float4 cbox[64];
  __shared__ float  car [64];
  __shared__ unsigned long long sup4[4];
  __shared__ unsigned long long conf4[4][64];
  __shared__ int s_nk;

  if (tid == 0) s_nk = 0;
  __syncthreads();
  int nk = 0;

  unsigned long long laneBitsBelow = (lane == 0) ? 0ull : (~0ull >> (64 - lane));

  for (int base = 0; base < Kb; base += 64) {
    int c = base + lane;
    bool active = (c < Kb);
    // degenerate box (0,0,-1,-1): area 0, inter 0 -> never conflicts
    float4 bx = active ? g_sbox[b][c] : make_float4(0.f, 0.f, -1.f, -1.f);
    float area = (bx.z - bx.x + 1.0f) * (bx.w - bx.y + 1.0f);
    if (wid == 0) { cbox[lane] = bx; car[lane] = area; }

    // suppression vs kept boxes: wave-strided (t % 4 == wid), unrolled x4
    int supp = active ? 0 : 1;
    {
      int t = wid;
      for (; t + 12 < nk; t += 16) {
        supp |= (int)iou_gt(bx, area, kbox[t],    kar[t]);
        supp |= (int)iou_gt(bx, area, kbox[t+4],  kar[t+4]);
        supp |= (int)iou_gt(bx, area, kbox[t+8],  kar[t+8]);
        supp |= (int)iou_gt(bx, area, kbox[t+12], kar[t+12]);
      }
      for (; t < nk; t += 4) supp |= (int)iou_gt(bx, area, kbox[t], kar[t]);
    }
    unsigned long long myb = __ballot(supp);
    if (lane == 0) sup4[wid] = myb;
    __syncthreads();   // cbox, car, sup4 ready

    // intra-chunk conflict bits: wave w covers j in [w*16, w*16+16)
    {
      unsigned long long confp = 0ull;
      for (int q = 0; q < 16; ++q) {
        int j = wid * 16 + q;
        if (iou_gt(bx, area, cbox[j], car[j])) confp |= (1ull << j);
      }
      conf4[wid][lane] = confp;
    }
    __syncthreads();   // conf4 ready

    if (wid == 0) {
      unsigned long long conf = (conf4[0][lane] | conf4[1][lane] |
                                 conf4[2][lane] | conf4[3][lane]) & laneBitsBelow;
      unsigned long long supAll = sup4[0] | sup4[1] | sup4[2] | sup4[3];
      unsigned long long pending = ~supAll;
      unsigned long long keptmask = 0ull;
      while (pending) {
        int i = __ffsll(pending) - 1;
        keptmask |= (1ull << i);
        unsigned long long confb = __ballot((int)((conf >> i) & 1ull));
        pending &= ~confb;
        pending &= ~(1ull << i);
      }
      int myPos = nk + __popcll(keptmask & laneBitsBelow);
      if (((keptmask >> lane) & 1ull) && myPos < post) {
        kbox[myPos] = bx;
        kar [myPos] = area;
        float* o = out + ((size_t)b * post + myPos) * 5;
        o[0] = (float)b; o[1] = bx.x; o[2] = bx.y; o[3] = bx.z; o[4] = bx.w;
      }
      if (lane == 0) s_nk = nk + __popcll(keptmask);
    }
    __syncthreads();   // s_nk, kbox, kar ready
    nk = s_nk;
    if (nk >= post) break;
  }

  nk = min(nk, post);
  for (int r = nk + tid; r < post; r += 256) {
    float* o = out + ((size_t)b * post + r) * 5;
    o[0] = (float)b; o[1] = 0.0f; o[2] = 0.0f; o[3] = 0.0f; o[4] = 0.0f;
  }
}

extern "C" void kernel_launch(void* const* d_in, const int* in_sizes, int n_in,
                              void* d_out, int out_size, void* d_ws, size_t ws_size,
                              hipStream_t stream) {
  const float* cls   = (const float*)d_in[0];
  const float* dlt   = (const float*)d_in[1];
  const float* ish   = (const float*)d_in[2];
  const int*   train = (const int*)d_in[3];
  float* out = (float*)d_out;

  int post = out_size / (NB * 5);  // 300 for TEST

  dim3 gdec(NPC / 256, NB);
  k_decode<<<gdec, 256, 0, stream>>>(cls, dlt, ish);

  k_pivot<<<NB, 256, 0, stream>>>(train);

  k_compact<<<gdec, 256, 0, stream>>>();

  dim3 grank(CAP / 256, NB);
  k_rank<<<grank, 256, 0, stream>>>(train);

  k_nms<<<NB, 256, 0, stream>>>(out, train, post);
}

// Round 4
// 195.800 us; speedup vs baseline: 1.9853x; 1.9853x over previous
//
#include <hip/hip_runtime.h>

// ProposalLayer for Faster R-CNN RPN on MI355X.
// B=4, H=64, W=96, A=9 anchors, N=55296 anchors/image.
// TEST cfg: pre=6000, post=300, thresh=0.7, min_size=16.

#define NB 4
#define AH 64
#define AW 96
#define NA 9
#define NPOS (AH*AW)        // 6144
#define NPC (NPOS*NA)       // 55296
#define CAP 16384           // candidate buffer per image
#define PREMAX 12000        // max 'pre' (TRAIN)
#define POSTMAX 2048        // max 'post' (TRAIN)
#define HSZ 65536           // 16-bit key-prefix histogram

// anchors from _generate_anchors(16, (0.5,1,2), (8,16,32)) — verified vs numpy
__constant__ float c_anchors[NA][4] = {
  { -84.f,  -40.f,  99.f,  55.f},
  {-176.f,  -88.f, 191.f, 103.f},
  {-360.f, -184.f, 375.f, 199.f},
  { -56.f,  -56.f,  71.f,  71.f},
  {-120.f, -120.f, 135.f, 135.f},
  {-248.f, -248.f, 263.f, 263.f},
  { -36.f,  -80.f,  51.f,  95.f},
  { -80.f, -168.f,  95.f, 183.f},
  {-168.f, -344.f, 183.f, 359.f},
};

// static scratch. Invariants maintained call-to-call: g_h16 zeroed by k_pivot
// after use; g_rank zeroed by k_nms's scatter after use; g_cnt zeroed by
// k_pivot before k_compact. First call sees .bss zeros.
__device__ unsigned int       g_keys[NB][NPC];    // storage order i2 = a*NPOS+pos
__device__ float4             g_boxes[NB][NPC];
__device__ unsigned int       g_h16[NB][HSZ];
__device__ unsigned int       g_pivot[NB];
__device__ int                g_cnt[NB];
__device__ unsigned long long g_cand[NB][CAP];    // key<<32 | ~iref (order)
__device__ int                g_cidx[NB][CAP];    // storage index i2 (box fetch)
__device__ int                g_rank[NB][CAP];
__device__ float4             g_sbox[NB][PREMAX];

// exact-equivalent "iou > 0.7f" without a division on the hot path:
// |inter - 0.7*denom| > 4e-6*denom decides the sign safely; the ~never-taken
// borderline falls back to the exact IEEE division the reference performs.
__device__ __forceinline__ bool iou_gt(float4 a, float areaA, float4 q, float areaQ) {
#pragma clang fp contract(off)
  float iw = fminf(a.z, q.z) - fmaxf(a.x, q.x) + 1.0f; iw = fmaxf(iw, 0.0f);
  float ih = fminf(a.w, q.w) - fmaxf(a.y, q.y) + 1.0f; ih = fmaxf(ih, 0.0f);
  float inter = iw * ih;
  float denom = areaA + areaQ - inter;
  float d = inter - 0.7f * denom;
  if (__builtin_expect(fabsf(d) <= 4e-6f * denom, 0))
    return (inter / denom) > 0.7f;
  return d > 0.0f;
}

// grid: (NA * NPOS/256, NB); a is block-uniform -> all global accesses coalesced
__global__ void __launch_bounds__(256) k_decode(const float* __restrict__ cls,
                                                const float* __restrict__ dlt,
                                                const float* __restrict__ ish) {
#pragma clang fp contract(off)
  int b   = blockIdx.y;
  int a   = blockIdx.x / (NPOS/256);                       // uniform
  int pos = (blockIdx.x % (NPOS/256)) * 256 + threadIdx.x; // contiguous
  int wx  = pos % AW;
  int hy  = pos / AW;

  float score = cls[(b * (2*NA) + NA + a) * NPOS + pos];
  const float* dp = dlt + (b * (4*NA) + a*4) * NPOS + pos;
  float d0 = dp[0];
  float d1 = dp[NPOS];
  float d2 = dp[2*NPOS];
  float d3 = dp[3*NPOS];

  float shx = (float)(wx * 16);
  float shy = (float)(hy * 16);
  float ax1 = c_anchors[a][0] + shx;
  float ay1 = c_anchors[a][1] + shy;
  float ax2 = c_anchors[a][2] + shx;
  float ay2 = c_anchors[a][3] + shy;

  float aw_ = ax2 - ax1 + 1.0f;
  float ah_ = ay2 - ay1 + 1.0f;
  float acx = ax1 + 0.5f * aw_;
  float acy = ay1 + 0.5f * ah_;

  float pcx = d0 * aw_ + acx;
  float pcy = d1 * ah_ + acy;
  float pw  = expf(d2) * aw_;
  float ph  = expf(d3) * ah_;

  float x1 = pcx - 0.5f * pw;
  float y1 = pcy - 0.5f * ph;
  float x2 = pcx + 0.5f * pw;
  float y2 = pcy + 0.5f * ph;

  float imh = ish[b*2 + 0];
  float imw = ish[b*2 + 1];
  x1 = fminf(fmaxf(x1, 0.0f), imw - 1.0f);
  x2 = fminf(fmaxf(x2, 0.0f), imw - 1.0f);
  y1 = fminf(fmaxf(y1, 0.0f), imh - 1.0f);
  y2 = fminf(fmaxf(y2, 0.0f), imh - 1.0f);

  bool valid = ((x2 - x1 + 1.0f) >= 16.0f) && ((y2 - y1 + 1.0f) >= 16.0f);

  int i2 = a * NPOS + pos;
  g_boxes[b][i2] = make_float4(x1, y1, x2, y2);

  unsigned int key = 0u;
  if (valid) {
    unsigned int ub = __float_as_uint(score);
    key = (ub >> 31) ? ~ub : (ub | 0x80000000u);  // monotonic flip; valid >= 0x00800000
  }
  g_keys[b][i2] = key;
  atomicAdd(&g_h16[b][key >> 16], 1u);            // key==0 -> bucket 0 (never selected)
}

// one block/image: pivot T = largest bucket with suffix>=pre from the 16-bit
// histogram; also re-zeroes g_h16 and g_cnt. Candidate count = pre + epsilon.
__global__ void __launch_bounds__(256) k_pivot(const int* __restrict__ train) {
  int b = blockIdx.x;
  int tid = threadIdx.x;
  unsigned int pre = train[0] ? 12000u : 6000u;
  const int CH = HSZ / 256;   // 256 buckets per thread
  __shared__ unsigned int csum[256];
  __shared__ unsigned int csuf[257];
  __shared__ int best;

  uint4* hp = (uint4*)&g_h16[b][tid * CH];
  unsigned int s = 0;
#pragma unroll
  for (int q = 0; q < CH/4; ++q) { uint4 v = hp[q]; s += v.x + v.y + v.z + v.w; }
  csum[tid] = s;
  if (tid == 0) { best = 0; g_cnt[b] = 0; }
  __syncthreads();
  if (tid == 0) {
    unsigned int run = 0;
    csuf[256] = 0;
    for (int c = 255; c >= 0; --c) { run += csum[c]; csuf[c] = run; }
  }
  __syncthreads();

  unsigned int run = csuf[tid + 1];
  int loc = 0;
  for (int q = CH - 1; q >= 0; --q) {
    run += g_h16[b][tid * CH + q];
    if (loc == 0 && run >= pre) {
      int T = tid * CH + q;
      if (T >= 1) loc = T;           // T=0 is the invalid bucket
    }
  }
  // zero this thread's chunk for the next call
  uint4 z = make_uint4(0u, 0u, 0u, 0u);
#pragma unroll
  for (int q = 0; q < CH/4; ++q) hp[q] = z;

  if (loc) atomicMax(&best, loc);
  __syncthreads();
  if (tid == 0)
    g_pivot[b] = best ? ((unsigned int)best << 16) : 1u;  // best==0: accept all valid
}

__global__ void __launch_bounds__(256) k_compact() {
  int b = blockIdx.y;
  int a   = blockIdx.x / (NPOS/256);                       // uniform
  int pos = (blockIdx.x % (NPOS/256)) * 256 + threadIdx.x;
  int i2 = a * NPOS + pos;
  unsigned int key = g_keys[b][i2];
  if (key >= g_pivot[b]) {           // pivot >= 1, so key==0 auto-excluded
    int p = atomicAdd(&g_cnt[b], 1);
    if (p < CAP) {
      unsigned int iref = (unsigned int)(pos * NA + a);    // reference flat order
      g_cand[b][p] = ((unsigned long long)key << 32) |
                     (unsigned long long)(0xFFFFFFFFu - iref);
      g_cidx[b][p] = i2;
    }
  }
}

// exact rank (descending key, ascending iref) via 256x256 tile sweep:
// 1024 persistent blocks grid-stride over (jt,kt) tiles, k-tile in LDS
// (broadcast reads), partial rank accumulated and atomically added.
__global__ void __launch_bounds__(256) k_rank() {
  int tid = threadIdx.x;
  __shared__ unsigned long long tl[256];
  for (int b = 0; b < NB; ++b) {
    int Cb = g_cnt[b]; if (Cb > CAP) Cb = CAP;
    int nt = (Cb + 255) >> 8;
    int tiles = nt * nt;
    for (int t = blockIdx.x; t < tiles; t += gridDim.x) {
      int jt = t / nt, kt = t - jt * nt;
      int k = kt * 256 + tid;
      tl[tid] = (k < Cb) ? g_cand[b][k] : 0ull;   // 0 pad: never > cj
      __syncthreads();
      int j = jt * 256 + tid;
      unsigned long long cj = (j < Cb) ? g_cand[b][j] : ~0ull;
      int r = 0;
#pragma unroll 8
      for (int q = 0; q < 256; ++q) r += (int)(tl[q] > cj);
      if (j < Cb && r) atomicAdd(&g_rank[b][j], r);
      __syncthreads();
    }
  }
}

// one block (8 waves) per image: scatter-to-sorted prologue, then batched
// greedy NMS (64 candidates/chunk), exact-equivalent to the serial scan.
__global__ void __launch_bounds__(512)
k_nms(float* __restrict__ out, const int* __restrict__ train, int post) {
#pragma clang fp contract(off)
  int b = blockIdx.x;
  int tid = threadIdx.x;
  int lane = tid & 63;
  int wid = tid >> 6;     // 8 waves
  int pre = train[0] ? 12000 : 6000;
  int Cb = g_cnt[b]; if (Cb > CAP) Cb = CAP;
  int Kb = min(pre, Cb);

  // ---- scatter candidates into sorted order; reset g_rank for next call
  for (int j = tid; j < Cb; j += 512) {
    int r = g_rank[b][j];
    g_rank[b][j] = 0;
    if (r < pre) {
      int i2 = g_cidx[b][j];
      g_sbox[b][r] = g_boxes[b][i2];
    }
  }
  __threadfence_block();
  __syncthreads();

  __shared__ float4 kbox[POSTMAX];
  __shared__ float  kar [POSTMAX];
  __shared__ float4 cbox[64];
  __shared__ float  car [64];
  __shared__ unsigned long long sup8[8];
  __shared__ unsigned long long conf8[8][64];
  __shared__ int s_nk;
  if (tid == 0) s_nk = 0;
  __syncthreads();
  int nk = 0;

  unsigned long long laneBitsBelow = (lane == 0) ? 0ull : (~0ull >> (64 - lane));

  for (int base = 0; base < Kb; base += 64) {
    int c = base + lane;
    bool active = (c < Kb);
    // degenerate box (0,0,-1,-1): area 0, inter 0 -> never conflicts
    float4 bx = active ? g_sbox[b][c] : make_float4(0.f, 0.f, -1.f, -1.f);
    float area = (bx.z - bx.x + 1.0f) * (bx.w - bx.y + 1.0f);
    if (wid == 0) { cbox[lane] = bx; car[lane] = area; }

    // suppression vs kept boxes: wave-strided (t % 8 == wid), unrolled x4
    int supp = active ? 0 : 1;
    {
      int t = wid;
      for (; t + 24 < nk; t += 32) {
        supp |= (int)iou_gt(bx, area, kbox[t],    kar[t]);
        supp |= (int)iou_gt(bx, area, kbox[t+8],  kar[t+8]);
        supp |= (int)iou_gt(bx, area, kbox[t+16], kar[t+16]);
        supp |= (int)iou_gt(bx, area, kbox[t+24], kar[t+24]);
      }
      for (; t < nk; t += 8) supp |= (int)iou_gt(bx, area, kbox[t], kar[t]);
    }
    unsigned long long myb = __ballot(supp);
    if (lane == 0) sup8[wid] = myb;
    __syncthreads();   // cbox, car, sup8 ready

    // intra-chunk conflict bits: wave w covers j in [w*8, w*8+8)
    {
      unsigned long long confp = 0ull;
#pragma unroll
      for (int q = 0; q < 8; ++q) {
        int j = wid * 8 + q;
        if (iou_gt(bx, area, cbox[j], car[j])) confp |= (1ull << j);
      }
      conf8[wid][lane] = confp;
    }
    __syncthreads();   // conf8 ready

    if (wid == 0) {
      unsigned long long conf = (conf8[0][lane] | conf8[1][lane] |
                                 conf8[2][lane] | conf8[3][lane] |
                                 conf8[4][lane] | conf8[5][lane] |
                                 conf8[6][lane] | conf8[7][lane]) & laneBitsBelow;
      unsigned long long supAll = sup8[0] | sup8[1] | sup8[2] | sup8[3] |
                                  sup8[4] | sup8[5] | sup8[6] | sup8[7];
      unsigned long long pending = ~supAll;
      unsigned long long keptmask = 0ull;
      while (pending) {
        int i = __ffsll(pending) - 1;
        keptmask |= (1ull << i);
        unsigned long long confb = __ballot((int)((conf >> i) & 1ull));
        pending &= ~confb;
        pending &= ~(1ull << i);
      }
      int myPos = nk + __popcll(keptmask & laneBitsBelow);
      if (((keptmask >> lane) & 1ull) && myPos < post) {
        kbox[myPos] = bx;
        kar [myPos] = area;
        float* o = out + ((size_t)b * post + myPos) * 5;
        o[0] = (float)b; o[1] = bx.x; o[2] = bx.y; o[3] = bx.z; o[4] = bx.w;
      }
      if (lane == 0) s_nk = nk + __popcll(keptmask);
    }
    __syncthreads();   // s_nk, kbox, kar ready
    nk = s_nk;
    if (nk >= post) break;
  }

  nk = min(nk, post);
  for (int r = nk + tid; r < post; r += 512) {
    float* o = out + ((size_t)b * post + r) * 5;
    o[0] = (float)b; o[1] = 0.0f; o[2] = 0.0f; o[3] = 0.0f; o[4] = 0.0f;
  }
}

extern "C" void kernel_launch(void* const* d_in, const int* in_sizes, int n_in,
                              void* d_out, int out_size, void* d_ws, size_t ws_size,
                              hipStream_t stream) {
  const float* cls   = (const float*)d_in[0];
  const float* dlt   = (const float*)d_in[1];
  const float* ish   = (const float*)d_in[2];
  const int*   train = (const int*)d_in[3];
  float* out = (float*)d_out;

  int post = out_size / (NB * 5);  // 300 for TEST

  dim3 gdec(NA * (NPOS/256), NB);  // 216 x 4
  k_decode<<<gdec, 256, 0, stream>>>(cls, dlt, ish);

  k_pivot<<<NB, 256, 0, stream>>>(train);

  k_compact<<<gdec, 256, 0, stream>>>();

  k_rank<<<1024, 256, 0, stream>>>();

  k_nms<<<NB, 512, 0, stream>>>(out, train, post);
}